// Round 3
// baseline (880.732 us; speedup 1.0000x reference)
//
#include <hip/hip_runtime.h>
#include <hip/hip_bf16.h>
#include <hip/hip_cooperative_groups.h>
#include <cstddef>

namespace cg = cooperative_groups;

// ---- problem constants ----
#define Bc   2
#define Lc   8192
#define TGT  6146          // L - RF, RF = 2046
#define NL   20            // layers
#define RCc  32
#define DCc  32
#define SCc  1024
#define ECc  512
#define OCc  256
#define KTOT (NL * DCc)    // 640
#define TTILES 49          // ceil(TGT/128)

typedef __attribute__((ext_vector_type(4))) float f32x4;
typedef __attribute__((ext_vector_type(8))) short bf16x8;
typedef __attribute__((ext_vector_type(4))) int i32x4;

// ============================================================
// K0: input 1x1 conv  (B,256,L) x (32,256) -> res (B,32,L)
// ============================================================
__global__ __launch_bounds__(256) void input_conv(
    const float* __restrict__ x,   // [B][256][L]
    const float* __restrict__ w,   // [32][256]
    float* __restrict__ res_out)   // [B][32][L]
{
    __shared__ float ws[32][256];
    __shared__ float xs[64][64];
    int tid = threadIdx.x;
    int b   = blockIdx.y;
    int t0  = blockIdx.x * 64;

    for (int idx = tid; idx < 32 * 256; idx += 256)
        ws[idx >> 8][idx & 255] = w[idx];

    int tl = tid & 63, qq = tid >> 6, oc0 = qq * 8;
    float acc[8] = {};

    for (int icc = 0; icc < 4; ++icc) {
        __syncthreads();
        for (int idx = tid; idx < 64 * 64; idx += 256) {
            int icl = idx >> 6, tll = idx & 63;
            xs[icl][tll] = x[((size_t)b * 256 + icc * 64 + icl) * Lc + t0 + tll];
        }
        __syncthreads();
        for (int icl = 0; icl < 64; icl += 4) {
            float x0 = xs[icl][tl], x1 = xs[icl + 1][tl];
            float x2 = xs[icl + 2][tl], x3 = xs[icl + 3][tl];
#pragma unroll
            for (int j = 0; j < 8; ++j) {
                const float4 w4 = *(const float4*)&ws[oc0 + j][icc * 64 + icl];
                acc[j] += w4.x * x0 + w4.y * x1 + w4.z * x2 + w4.w * x3;
            }
        }
    }
#pragma unroll
    for (int j = 0; j < 8; ++j)
        res_out[((size_t)b * 32 + oc0 + j) * Lc + t0 + tl] = acc[j];
}

// ============================================================
// Cooperative kernel: all 20 residual layers.
// 256 blocks x 512 threads. Block = (batch b, 64-t tile).
// Residual tile lives in LDS; dilated halo read from ping-pong
// global mirrors; one grid.sync() per layer boundary.
// ============================================================
__global__ __launch_bounds__(512) void layers_coop(
    float* __restrict__ mir0,            // [B][32][L]  pre-filled by input_conv
    float* __restrict__ mir1,            // scratch mirror
    __hip_bfloat16* __restrict__ outsT,  // [B*TGT][640]
    const float* __restrict__ filter_w,  // [NL][32][32][2]
    const float* __restrict__ gate_w,    // [NL][32][32][2]
    const float* __restrict__ res_w,     // [NL][32][32]
    const float* __restrict__ cond,      // [B][5]
    const float* __restrict__ gcf_w,     // [NL][5]
    const float* __restrict__ gcs_w)     // [NL][5]
{
    __shared__ __align__(16) float wfg[32][32][4];  // f0,f1,g0,g1
    __shared__ float wr[32][32];
    __shared__ float cur[32][64];
    __shared__ float xms[32][64];
    __shared__ float osh[32][64];

    cg::grid_group grid = cg::this_grid();

    int tid = threadIdx.x;
    int bid = blockIdx.x;
    int b   = bid >> 7;            // 128 tiles per batch
    int t0  = (bid & 127) * 64;

    int tl = tid & 63, q = tid >> 6, oc0 = q * 4;

    // init residual tile from mirror0
    for (int idx = tid; idx < 32 * 64; idx += 512) {
        int ic = idx >> 6, tll = idx & 63;
        cur[ic][tll] = mir0[((size_t)b * 32 + ic) * Lc + t0 + tll];
    }
    float c0 = cond[b * 5 + 0], c1 = cond[b * 5 + 1], c2 = cond[b * 5 + 2],
          c3 = cond[b * 5 + 3], c4 = cond[b * 5 + 4];

    float* mir_r = mir0;
    float* mir_w = mir1;

    for (int li = 0; li < NL; ++li) {
        int d = 1 << (li % 10);
        const float* filt = filter_w + (size_t)li * 2048;
        const float* gate = gate_w   + (size_t)li * 2048;
        const float* rsw  = res_w    + (size_t)li * 1024;

        // ---- stage weights ----
        for (int idx = tid; idx < 4096; idx += 512) {
            int oc = idx >> 7, ic = (idx >> 2) & 31, s = idx & 3;
            wfg[oc][ic][s] = (s < 2) ? filt[(oc * 32 + ic) * 2 + s]
                                     : gate[(oc * 32 + ic) * 2 + (s - 2)];
        }
        for (int idx = tid; idx < 1024; idx += 512)
            wr[idx >> 5][idx & 31] = rsw[idx];
        // ---- dilated halo (layer li-1 residual at t-d) ----
        for (int idx = tid; idx < 2048; idx += 512) {
            int ic = idx >> 6, tll = idx & 63;
            int tm = t0 + tll - d;
            xms[ic][tll] = (tm >= 0) ? mir_r[((size_t)b * 32 + ic) * Lc + tm] : 0.f;
        }
        __syncthreads();

        float gf = gcf_w[li * 5 + 0] * c0 + gcf_w[li * 5 + 1] * c1 + gcf_w[li * 5 + 2] * c2 +
                   gcf_w[li * 5 + 3] * c3 + gcf_w[li * 5 + 4] * c4;
        float gg = gcs_w[li * 5 + 0] * c0 + gcs_w[li * 5 + 1] * c1 + gcs_w[li * 5 + 2] * c2 +
                   gcs_w[li * 5 + 3] * c3 + gcs_w[li * 5 + 4] * c4;

        float facc[4], gacc[4];
#pragma unroll
        for (int j = 0; j < 4; ++j) { facc[j] = gf; gacc[j] = gg; }

        for (int ic = 0; ic < 32; ++ic) {
            float xm = xms[ic][tl];
            float x0 = cur[ic][tl];
#pragma unroll
            for (int j = 0; j < 4; ++j) {
                const float4 w4 = *(const float4*)&wfg[oc0 + j][ic][0];
                facc[j] += w4.x * xm + w4.y * x0;
                gacc[j] += w4.z * xm + w4.w * x0;
            }
        }
#pragma unroll
        for (int j = 0; j < 4; ++j) {
            float th = 1.f - 2.f / (expf(2.f * facc[j]) + 1.f);  // tanh
            float sg = 1.f / (1.f + expf(-gacc[j]));             // sigmoid
            osh[oc0 + j][tl] = th * sg;
        }
        __syncthreads();

        // ---- skip-output store (bf16, time-major) ----
        if (tid < 256) {
            int tt = tid & 63, g8 = tid >> 6, oc8 = g8 * 8;
            int t = t0 + tt;
            if (t >= Lc - TGT) {
                int ts = t - (Lc - TGT);
                union { i32x4 v; __hip_bfloat16 h[8]; } u;
#pragma unroll
                for (int jj = 0; jj < 8; ++jj)
                    u.h[jj] = __float2bfloat16(osh[oc8 + jj][tt]);
                *(i32x4*)(outsT + ((size_t)(b * TGT + ts)) * KTOT + li * 32 + oc8) = u.v;
            }
        }

        if (li + 1 < NL) {
            // ---- residual conv + update ----
            float racc[4];
#pragma unroll
            for (int j = 0; j < 4; ++j) racc[j] = cur[oc0 + j][tl];
            for (int ic = 0; ic < 32; ++ic) {
                float ov = osh[ic][tl];
#pragma unroll
                for (int j = 0; j < 4; ++j) racc[j] += wr[oc0 + j][ic] * ov;
            }
            __syncthreads();   // all reads of cur done
#pragma unroll
            for (int j = 0; j < 4; ++j) {
                cur[oc0 + j][tl] = racc[j];
                mir_w[((size_t)b * 32 + oc0 + j) * Lc + t0 + tl] = racc[j];
            }
            grid.sync();
            float* tmp = mir_r; mir_r = mir_w; mir_w = tmp;
        }
    }
}

// ============================================================
// weight packs (fp32 -> bf16, [M][K] row-major)
// ============================================================
__global__ void pack_w1(const float* __restrict__ sw, __hip_bfloat16* __restrict__ d)
{
    int idx = blockIdx.x * 256 + threadIdx.x;
    if (idx >= SCc * KTOT) return;
    int m = idx / KTOT, k = idx % KTOT;
    int i = k >> 5, c = k & 31;
    d[idx] = __float2bfloat16(sw[((size_t)i * SCc + m) * DCc + c]);
}

__global__ void pack_plain(const float* __restrict__ s, __hip_bfloat16* __restrict__ d, int n)
{
    int idx = blockIdx.x * 256 + threadIdx.x;
    if (idx < n) d[idx] = __float2bfloat16(s[idx]);
}

// ============================================================
// bf16 MFMA GEMM: Y[t][m] = sum_k X[t][k] * W[m][k]  (+bias, relu)
// ============================================================
template <bool RELU_OUT, bool OUT_BF16>
__global__ __launch_bounds__(256) void gemm_mfma(
    const __hip_bfloat16* __restrict__ X,
    const __hip_bfloat16* __restrict__ W,
    const float* __restrict__ bias,
    void* __restrict__ Y,
    int M, int K)
{
    __shared__ i32x4 Xs[128 * 8];
    __shared__ i32x4 Ws[128 * 8];

    int tid = threadIdx.x;
    int m0  = blockIdx.x * 128;
    int by  = blockIdx.y;
    int b   = by / TTILES;
    int t0  = (by % TTILES) * 128;

    int lane = tid & 63, wid = tid >> 6;
    int wy = wid >> 1, wx = wid & 1;
    int r15 = lane & 15, q = lane >> 4;

    int sr = tid >> 1, hf = tid & 1;
    int xrow = t0 + sr; if (xrow > TGT - 1) xrow = TGT - 1;
    const i32x4* gx = (const i32x4*)(X + ((size_t)(b * TGT + xrow)) * K) + hf * 4;
    const i32x4* gw = (const i32x4*)(W + ((size_t)(m0 + sr)) * K) + hf * 4;
    int wslot[4];
#pragma unroll
    for (int g = 0; g < 4; ++g) wslot[g] = sr * 8 + ((hf * 4 + g) ^ (sr & 7));

    f32x4 acc[4][4] = {};

    i32x4 rx[4], rw[4];
#pragma unroll
    for (int g = 0; g < 4; ++g) { rx[g] = gx[g]; rw[g] = gw[g]; }

    const int nkt = K >> 6;
    for (int kt = 0; kt < nkt; ++kt) {
        __syncthreads();
#pragma unroll
        for (int g = 0; g < 4; ++g) { Xs[wslot[g]] = rx[g]; Ws[wslot[g]] = rw[g]; }
        __syncthreads();
        if (kt + 1 < nkt) {
            gx += 8; gw += 8;
#pragma unroll
            for (int g = 0; g < 4; ++g) { rx[g] = gx[g]; rw[g] = gw[g]; }
        }
        const bf16x8* Xv = (const bf16x8*)Xs;
        const bf16x8* Wv = (const bf16x8*)Ws;
#pragma unroll
        for (int kk = 0; kk < 2; ++kk) {
            int sg = (kk * 4 + q) ^ (r15 & 7);
            bf16x8 af[4], bw[4];
#pragma unroll
            for (int ft = 0; ft < 4; ++ft)
                af[ft] = Xv[(wy * 64 + ft * 16 + r15) * 8 + sg];
#pragma unroll
            for (int fj = 0; fj < 4; ++fj)
                bw[fj] = Wv[(wx * 64 + fj * 16 + r15) * 8 + sg];
#pragma unroll
            for (int ft = 0; ft < 4; ++ft)
#pragma unroll
                for (int fj = 0; fj < 4; ++fj)
                    acc[ft][fj] = __builtin_amdgcn_mfma_f32_16x16x32_bf16(
                        af[ft], bw[fj], acc[ft][fj], 0, 0, 0);
        }
    }

#pragma unroll
    for (int ft = 0; ft < 4; ++ft) {
#pragma unroll
        for (int r = 0; r < 4; ++r) {
            int t = t0 + wy * 64 + ft * 16 + q * 4 + r;
            if (t < TGT) {
                size_t rowoff = ((size_t)(b * TGT + t)) * M;
#pragma unroll
                for (int fj = 0; fj < 4; ++fj) {
                    int m = m0 + wx * 64 + fj * 16 + r15;
                    float v = acc[ft][fj][r];
                    if (bias) v += bias[m];
                    if (RELU_OUT) v = fmaxf(v, 0.f);
                    if (OUT_BF16)
                        ((__hip_bfloat16*)Y)[rowoff + m] = __float2bfloat16(v);
                    else
                        ((float*)Y)[rowoff + m] = v;
                }
            }
        }
    }
}

// ============================================================
extern "C" void kernel_launch(void* const* d_in, const int* in_sizes, int n_in,
                              void* d_out, int out_size, void* d_ws, size_t ws_size,
                              hipStream_t stream)
{
    const float* inputs   = (const float*)d_in[0];
    const float* cond     = (const float*)d_in[1];
    const float* input_w  = (const float*)d_in[2];
    const float* filter_w = (const float*)d_in[3];
    const float* gate_w   = (const float*)d_in[4];
    const float* res_w    = (const float*)d_in[5];
    const float* split_w  = (const float*)d_in[6];
    const float* gcf_w    = (const float*)d_in[7];
    const float* gcs_w    = (const float*)d_in[8];
    const float* f1_w     = (const float*)d_in[9];
    const float* f1_b     = (const float*)d_in[10];
    const float* f2_w     = (const float*)d_in[11];
    const float* f2_b     = (const float*)d_in[12];
    float* out = (float*)d_out;

    char* wsb = (char*)d_ws;
    const size_t RES_B   = (size_t)Bc * RCc * Lc * 4;        // 2 MB each
    const size_t OUTS_B  = (size_t)Bc * TGT * KTOT * 2;      // 15.7 MB
    const size_t FIN_B   = (size_t)Bc * TGT * SCc * 2;       // 25.2 MB
    const size_t H1_B    = (size_t)Bc * TGT * ECc * 2;       // 12.6 MB
    const size_t W1_B    = (size_t)SCc * KTOT * 2;
    const size_t W2_B    = (size_t)ECc * SCc * 2;

    float* res0              = (float*)wsb;                   size_t off = RES_B;
    float* res1              = (float*)(wsb + off);           off += RES_B;
    __hip_bfloat16* outsT    = (__hip_bfloat16*)(wsb + off);  off += OUTS_B;
    __hip_bfloat16* finalT   = (__hip_bfloat16*)(wsb + off);  off += FIN_B;
    __hip_bfloat16* h1T      = (__hip_bfloat16*)(wsb + off);  off += H1_B;
    __hip_bfloat16* Wp1      = (__hip_bfloat16*)(wsb + off);  off += W1_B;
    __hip_bfloat16* Wp2      = (__hip_bfloat16*)(wsb + off);  off += W2_B;
    __hip_bfloat16* Wp3      = (__hip_bfloat16*)(wsb + off);

    // weight packs (independent of activations)
    pack_w1<<<(SCc * KTOT + 255) / 256, 256, 0, stream>>>(split_w, Wp1);
    pack_plain<<<(ECc * SCc + 255) / 256, 256, 0, stream>>>(f1_w, Wp2, ECc * SCc);
    pack_plain<<<(OCc * ECc + 255) / 256, 256, 0, stream>>>(f2_w, Wp3, OCc * ECc);

    input_conv<<<dim3(Lc / 64, Bc), 256, 0, stream>>>(inputs, input_w, res0);

    // all 20 layers in one cooperative kernel
    {
        float* mir0 = res0;
        float* mir1 = res1;
        __hip_bfloat16* outsT_a = outsT;
        const float* fw = filter_w; const float* gw = gate_w; const float* rw = res_w;
        const float* cd = cond; const float* gf = gcf_w; const float* gs = gcs_w;
        void* args[] = { &mir0, &mir1, &outsT_a, &fw, &gw, &rw, &cd, &gf, &gs };
        hipLaunchCooperativeKernel((void*)layers_coop, dim3(256), dim3(512),
                                   args, 0, stream);
    }

    // G1: finalT = relu( outsT(12292x640) @ Wp1^T )   -> bf16 [t][1024]
    gemm_mfma<true, true><<<dim3(SCc / 128, Bc * TTILES), 256, 0, stream>>>(
        outsT, Wp1, nullptr, finalT, SCc, KTOT);

    // G2: h1T = relu( finalT @ Wp2^T + f1_b )         -> bf16 [t][512]
    gemm_mfma<true, true><<<dim3(ECc / 128, Bc * TTILES), 256, 0, stream>>>(
        finalT, Wp2, f1_b, h1T, ECc, SCc);

    // G3: out = h1T @ Wp3^T + f2_b                    -> fp32 [t][256] (final layout)
    gemm_mfma<false, false><<<dim3(OCc / 128, Bc * TTILES), 256, 0, stream>>>(
        h1T, Wp3, f2_b, out, OCc, ECc);
}

// Round 4
// 308.804 us; speedup vs baseline: 2.8521x; 2.8521x over previous
//
#include <hip/hip_runtime.h>
#include <hip/hip_bf16.h>
#include <cstddef>

// ---- problem constants ----
#define Bc   2
#define Lc   8192
#define TGT  6146          // L - RF, RF = 2046
#define NL   20            // layers
#define RCc  32
#define DCc  32
#define SCc  1024
#define ECc  512
#define OCc  256
#define KTOT (NL * DCc)    // 640
#define TTILES 49          // ceil(TGT/128)

typedef __attribute__((ext_vector_type(4))) float f32x4;
typedef __attribute__((ext_vector_type(8))) short bf16x8;
typedef __attribute__((ext_vector_type(4))) int i32x4;
typedef __attribute__((ext_vector_type(2))) int i32x2;

// ============================================================
// K0: input 1x1 conv  (B,256,L) x (32,256) -> res (B,32,L)
// ============================================================
__global__ __launch_bounds__(256) void input_conv(
    const float* __restrict__ x,   // [B][256][L]
    const float* __restrict__ w,   // [32][256]
    float* __restrict__ res_out)   // [B][32][L]
{
    __shared__ float ws[32][256];
    __shared__ float xs[64][64];
    int tid = threadIdx.x;
    int b   = blockIdx.y;
    int t0  = blockIdx.x * 64;

    for (int idx = tid; idx < 32 * 256; idx += 256)
        ws[idx >> 8][idx & 255] = w[idx];

    int tl = tid & 63, qq = tid >> 6, oc0 = qq * 8;
    float acc[8] = {};

    for (int icc = 0; icc < 4; ++icc) {
        __syncthreads();
        for (int idx = tid; idx < 64 * 64; idx += 256) {
            int icl = idx >> 6, tll = idx & 63;
            xs[icl][tll] = x[((size_t)b * 256 + icc * 64 + icl) * Lc + t0 + tll];
        }
        __syncthreads();
        for (int icl = 0; icl < 64; icl += 4) {
            float x0 = xs[icl][tl], x1 = xs[icl + 1][tl];
            float x2 = xs[icl + 2][tl], x3 = xs[icl + 3][tl];
#pragma unroll
            for (int j = 0; j < 8; ++j) {
                const float4 w4 = *(const float4*)&ws[oc0 + j][icc * 64 + icl];
                acc[j] += w4.x * x0 + w4.y * x1 + w4.z * x2 + w4.w * x3;
            }
        }
    }
#pragma unroll
    for (int j = 0; j < 8; ++j)
        res_out[((size_t)b * 32 + oc0 + j) * Lc + t0 + tl] = acc[j];
}

// ============================================================
// per-layer v2: 512 thr, 64-t tile, 4 oc/thread.
// x column in registers (coalesced global loads, L2-hot);
// weights transposed in LDS -> wave-uniform float4 broadcasts.
// ============================================================
template <bool SKIPRES>
__global__ __launch_bounds__(512) void layer_v2(
    const float* __restrict__ res_in,   // [B][32][L]
    float* __restrict__ res_out,        // [B][32][L]
    __hip_bfloat16* __restrict__ outsT, // [B*TGT][640]
    const float* __restrict__ filt,     // [32][32][2]
    const float* __restrict__ gate,     // [32][32][2]
    const float* __restrict__ resw,     // [32][32]
    const float* __restrict__ cond,     // [B][5]
    const float* __restrict__ gcf,      // [5]
    const float* __restrict__ gcs,      // [5]
    int dil, int li)
{
    __shared__ __align__(16) float sFT[2][32][32];  // [tap][ic][oc]
    __shared__ __align__(16) float sGT[2][32][32];
    __shared__ __align__(16) float sRT[32][32];     // [ic][oc]
    __shared__ float osh[32][64];

    int tid = threadIdx.x;
    int b   = blockIdx.y;
    int t0  = blockIdx.x * 64;
    int tl  = tid & 63, q = tid >> 6;   // q in 0..7
    int oc0 = q * 4;
    int t   = t0 + tl;

    // stage weights (coalesced global reads, transposed LDS writes)
    for (int idx = tid; idx < 2048; idx += 512) {
        int oc = idx >> 6, ic = (idx >> 1) & 31, s = idx & 1;
        sFT[s][ic][oc] = filt[idx];
        sGT[s][ic][oc] = gate[idx];
    }
    for (int idx = tid; idx < 1024; idx += 512)
        sRT[idx & 31][idx >> 5] = resw[idx];

    // x column into registers (coalesced per-ic loads)
    const float* rbase = res_in + (size_t)b * 32 * Lc + t;
    int tm = t - dil;
    float x0[32], xm[32];
#pragma unroll
    for (int ic = 0; ic < 32; ++ic) {
        x0[ic] = rbase[ic * Lc];
        xm[ic] = (tm >= 0) ? rbase[ic * Lc - dil] : 0.f;
    }

    float gf = gcf[0] * cond[b * 5 + 0] + gcf[1] * cond[b * 5 + 1] +
               gcf[2] * cond[b * 5 + 2] + gcf[3] * cond[b * 5 + 3] +
               gcf[4] * cond[b * 5 + 4];
    float gg = gcs[0] * cond[b * 5 + 0] + gcs[1] * cond[b * 5 + 1] +
               gcs[2] * cond[b * 5 + 2] + gcs[3] * cond[b * 5 + 3] +
               gcs[4] * cond[b * 5 + 4];

    __syncthreads();   // weights staged

    float facc[4], gacc[4];
#pragma unroll
    for (int j = 0; j < 4; ++j) { facc[j] = gf; gacc[j] = gg; }

#pragma unroll
    for (int ic = 0; ic < 32; ++ic) {
        const float4 f0 = *(const float4*)&sFT[0][ic][oc0];
        const float4 f1 = *(const float4*)&sFT[1][ic][oc0];
        const float4 g0 = *(const float4*)&sGT[0][ic][oc0];
        const float4 g1 = *(const float4*)&sGT[1][ic][oc0];
        float a = xm[ic], c = x0[ic];
        facc[0] += f0.x * a + f1.x * c;  gacc[0] += g0.x * a + g1.x * c;
        facc[1] += f0.y * a + f1.y * c;  gacc[1] += g0.y * a + g1.y * c;
        facc[2] += f0.z * a + f1.z * c;  gacc[2] += g0.z * a + g1.z * c;
        facc[3] += f0.w * a + f1.w * c;  gacc[3] += g0.w * a + g1.w * c;
    }

    float o[4];
#pragma unroll
    for (int j = 0; j < 4; ++j) {
        float th = 1.f - 2.f / (__expf(2.f * facc[j]) + 1.f);  // tanh
        float sg = 1.f / (1.f + __expf(-gacc[j]));             // sigmoid
        o[j] = th * sg;
        osh[oc0 + j][tl] = o[j];
    }

    // skip-output store (bf16, time-major), 8B per thread
    if (t >= Lc - TGT) {
        int ts = t - (Lc - TGT);
        union { i32x2 v; __hip_bfloat16 h[4]; } u;
#pragma unroll
        for (int j = 0; j < 4; ++j) u.h[j] = __float2bfloat16(o[j]);
        *(i32x2*)(outsT + ((size_t)(b * TGT + ts)) * KTOT + li * 32 + oc0) = u.v;
    }

    if (!SKIPRES) {
        __syncthreads();   // osh complete
        float racc[4];
#pragma unroll
        for (int j = 0; j < 4; ++j) racc[j] = rbase[(oc0 + j) * Lc];
#pragma unroll
        for (int ic = 0; ic < 32; ++ic) {
            float ov = osh[ic][tl];
            const float4 w4 = *(const float4*)&sRT[ic][oc0];
            racc[0] += w4.x * ov;
            racc[1] += w4.y * ov;
            racc[2] += w4.z * ov;
            racc[3] += w4.w * ov;
        }
#pragma unroll
        for (int j = 0; j < 4; ++j)
            res_out[((size_t)b * 32 + oc0 + j) * Lc + t] = racc[j];
    }
}

// ============================================================
// weight packs (fp32 -> bf16, [M][K] row-major)
// ============================================================
__global__ void pack_w1(const float* __restrict__ sw, __hip_bfloat16* __restrict__ d)
{
    int idx = blockIdx.x * 256 + threadIdx.x;
    if (idx >= SCc * KTOT) return;
    int m = idx / KTOT, k = idx % KTOT;
    int i = k >> 5, c = k & 31;
    d[idx] = __float2bfloat16(sw[((size_t)i * SCc + m) * DCc + c]);
}

__global__ void pack_plain(const float* __restrict__ s, __hip_bfloat16* __restrict__ d, int n)
{
    int idx = blockIdx.x * 256 + threadIdx.x;
    if (idx < n) d[idx] = __float2bfloat16(s[idx]);
}

// ============================================================
// bf16 MFMA GEMM: Y[t][m] = sum_k X[t][k] * W[m][k]  (+bias, relu)
// ============================================================
template <bool RELU_OUT, bool OUT_BF16>
__global__ __launch_bounds__(256) void gemm_mfma(
    const __hip_bfloat16* __restrict__ X,
    const __hip_bfloat16* __restrict__ W,
    const float* __restrict__ bias,
    void* __restrict__ Y,
    int M, int K)
{
    __shared__ i32x4 Xs[128 * 8];
    __shared__ i32x4 Ws[128 * 8];

    int tid = threadIdx.x;
    int m0  = blockIdx.x * 128;
    int by  = blockIdx.y;
    int b   = by / TTILES;
    int t0  = (by % TTILES) * 128;

    int lane = tid & 63, wid = tid >> 6;
    int wy = wid >> 1, wx = wid & 1;
    int r15 = lane & 15, q = lane >> 4;

    int sr = tid >> 1, hf = tid & 1;
    int xrow = t0 + sr; if (xrow > TGT - 1) xrow = TGT - 1;
    const i32x4* gx = (const i32x4*)(X + ((size_t)(b * TGT + xrow)) * K) + hf * 4;
    const i32x4* gw = (const i32x4*)(W + ((size_t)(m0 + sr)) * K) + hf * 4;
    int wslot[4];
#pragma unroll
    for (int g = 0; g < 4; ++g) wslot[g] = sr * 8 + ((hf * 4 + g) ^ (sr & 7));

    f32x4 acc[4][4] = {};

    i32x4 rx[4], rw[4];
#pragma unroll
    for (int g = 0; g < 4; ++g) { rx[g] = gx[g]; rw[g] = gw[g]; }

    const int nkt = K >> 6;
    for (int kt = 0; kt < nkt; ++kt) {
        __syncthreads();
#pragma unroll
        for (int g = 0; g < 4; ++g) { Xs[wslot[g]] = rx[g]; Ws[wslot[g]] = rw[g]; }
        __syncthreads();
        if (kt + 1 < nkt) {
            gx += 8; gw += 8;
#pragma unroll
            for (int g = 0; g < 4; ++g) { rx[g] = gx[g]; rw[g] = gw[g]; }
        }
        const bf16x8* Xv = (const bf16x8*)Xs;
        const bf16x8* Wv = (const bf16x8*)Ws;
#pragma unroll
        for (int kk = 0; kk < 2; ++kk) {
            int sg = (kk * 4 + q) ^ (r15 & 7);
            bf16x8 af[4], bw[4];
#pragma unroll
            for (int ft = 0; ft < 4; ++ft)
                af[ft] = Xv[(wy * 64 + ft * 16 + r15) * 8 + sg];
#pragma unroll
            for (int fj = 0; fj < 4; ++fj)
                bw[fj] = Wv[(wx * 64 + fj * 16 + r15) * 8 + sg];
#pragma unroll
            for (int ft = 0; ft < 4; ++ft)
#pragma unroll
                for (int fj = 0; fj < 4; ++fj)
                    acc[ft][fj] = __builtin_amdgcn_mfma_f32_16x16x32_bf16(
                        af[ft], bw[fj], acc[ft][fj], 0, 0, 0);
        }
    }

#pragma unroll
    for (int ft = 0; ft < 4; ++ft) {
#pragma unroll
        for (int r = 0; r < 4; ++r) {
            int t = t0 + wy * 64 + ft * 16 + q * 4 + r;
            if (t < TGT) {
                size_t rowoff = ((size_t)(b * TGT + t)) * M;
#pragma unroll
                for (int fj = 0; fj < 4; ++fj) {
                    int m = m0 + wx * 64 + fj * 16 + r15;
                    float v = acc[ft][fj][r];
                    if (bias) v += bias[m];
                    if (RELU_OUT) v = fmaxf(v, 0.f);
                    if (OUT_BF16)
                        ((__hip_bfloat16*)Y)[rowoff + m] = __float2bfloat16(v);
                    else
                        ((float*)Y)[rowoff + m] = v;
                }
            }
        }
    }
}

// ============================================================
extern "C" void kernel_launch(void* const* d_in, const int* in_sizes, int n_in,
                              void* d_out, int out_size, void* d_ws, size_t ws_size,
                              hipStream_t stream)
{
    const float* inputs   = (const float*)d_in[0];
    const float* cond     = (const float*)d_in[1];
    const float* input_w  = (const float*)d_in[2];
    const float* filter_w = (const float*)d_in[3];
    const float* gate_w   = (const float*)d_in[4];
    const float* res_w    = (const float*)d_in[5];
    const float* split_w  = (const float*)d_in[6];
    const float* gcf_w    = (const float*)d_in[7];
    const float* gcs_w    = (const float*)d_in[8];
    const float* f1_w     = (const float*)d_in[9];
    const float* f1_b     = (const float*)d_in[10];
    const float* f2_w     = (const float*)d_in[11];
    const float* f2_b     = (const float*)d_in[12];
    float* out = (float*)d_out;

    char* wsb = (char*)d_ws;
    const size_t RES_B   = (size_t)Bc * RCc * Lc * 4;        // 2 MB each
    const size_t OUTS_B  = (size_t)Bc * TGT * KTOT * 2;      // 15.7 MB
    const size_t FIN_B   = (size_t)Bc * TGT * SCc * 2;       // 25.2 MB
    const size_t H1_B    = (size_t)Bc * TGT * ECc * 2;       // 12.6 MB
    const size_t W1_B    = (size_t)SCc * KTOT * 2;
    const size_t W2_B    = (size_t)ECc * SCc * 2;

    float* res0              = (float*)wsb;                   size_t off = RES_B;
    float* res1              = (float*)(wsb + off);           off += RES_B;
    __hip_bfloat16* outsT    = (__hip_bfloat16*)(wsb + off);  off += OUTS_B;
    __hip_bfloat16* finalT   = (__hip_bfloat16*)(wsb + off);  off += FIN_B;
    __hip_bfloat16* h1T      = (__hip_bfloat16*)(wsb + off);  off += H1_B;
    __hip_bfloat16* Wp1      = (__hip_bfloat16*)(wsb + off);  off += W1_B;
    __hip_bfloat16* Wp2      = (__hip_bfloat16*)(wsb + off);  off += W2_B;
    __hip_bfloat16* Wp3      = (__hip_bfloat16*)(wsb + off);

    // weight packs (independent of activations)
    pack_w1<<<(SCc * KTOT + 255) / 256, 256, 0, stream>>>(split_w, Wp1);
    pack_plain<<<(ECc * SCc + 255) / 256, 256, 0, stream>>>(f1_w, Wp2, ECc * SCc);
    pack_plain<<<(OCc * ECc + 255) / 256, 256, 0, stream>>>(f2_w, Wp3, OCc * ECc);

    input_conv<<<dim3(Lc / 64, Bc), 256, 0, stream>>>(inputs, input_w, res0);

    float* rin = res0;
    float* rout = res1;
    for (int i = 0; i < NL; ++i) {
        int d = 1 << (i % 10);
        if (i + 1 < NL)
            layer_v2<false><<<dim3(Lc / 64, Bc), 512, 0, stream>>>(
                rin, rout, outsT,
                filter_w + (size_t)i * DCc * RCc * 2,
                gate_w   + (size_t)i * DCc * RCc * 2,
                res_w    + (size_t)i * RCc * DCc,
                cond, gcf_w + i * 5, gcs_w + i * 5, d, i);
        else
            layer_v2<true><<<dim3(Lc / 64, Bc), 512, 0, stream>>>(
                rin, rout, outsT,
                filter_w + (size_t)i * DCc * RCc * 2,
                gate_w   + (size_t)i * DCc * RCc * 2,
                res_w    + (size_t)i * RCc * DCc,
                cond, gcf_w + i * 5, gcs_w + i * 5, d, i);
        float* tmp = rin; rin = rout; rout = tmp;
    }

    // G1: finalT = relu( outsT(12292x640) @ Wp1^T )   -> bf16 [t][1024]
    gemm_mfma<true, true><<<dim3(SCc / 128, Bc * TTILES), 256, 0, stream>>>(
        outsT, Wp1, nullptr, finalT, SCc, KTOT);

    // G2: h1T = relu( finalT @ Wp2^T + f1_b )         -> bf16 [t][512]
    gemm_mfma<true, true><<<dim3(ECc / 128, Bc * TTILES), 256, 0, stream>>>(
        finalT, Wp2, f1_b, h1T, ECc, SCc);

    // G3: out = h1T @ Wp3^T + f2_b                    -> fp32 [t][256] (final layout)
    gemm_mfma<false, false><<<dim3(OCc / 128, Bc * TTILES), 256, 0, stream>>>(
        h1T, Wp3, f2_b, out, OCc, ECc);
}